// Round 19
// baseline (93.155 us; speedup 1.0000x reference)
//
#include <hip/hip_runtime.h>
#include <hip/hip_bf16.h>
#include <math.h>

#define BB 16
#define HH 256
#define WW 256

// ws layout in floats
#define OFF_CHSUM 0      // [64]
#define OFF_CHSQ  64     // [64]
#define OFF_FEAT  256    // [16*64] pooled relu sums (pre-division)
#define OFF_Z     2048   // [16*256*256] z = sum_a g[a]*xh[px][a]

// shared-memory pool byte offsets (conv path)
#define SM_PAN   0                   // unsigned[7*776]  = 21728 B
#define SM_W     21728               // float[1728]      =  6912 B
#define SM_B     28640               // float[64]        =   256 B
#define SM_RED   28896               // float[4][4][16][2] = 2048 B -> 30944
// z path: float[256*31] = 31744 B at 0; g table at 31744 (+128)
#define SM_G     31744
#define SM_BYTES 32000

// z split between the two passes (32 z-units of 2048 px per image)
#define ZP1 22    // pass-1 z-units (blockIdx.x in [64, 64+ZP1))
#define ZP2 10    // pass-2 z-units (blockIdx.x in [64, 64+ZP2) -> zx += ZP1)

typedef __attribute__((ext_vector_type(8))) short bf16x8;
typedef __attribute__((ext_vector_type(4))) float f32x4;

union BFu { __hip_bfloat16 h; short s; };
union ABu { bf16x8 v; unsigned u[4]; };

__device__ __forceinline__ unsigned packsplit(float v) {
    BFu hi; hi.h = __float2bfloat16(v);
    float rs = v - __bfloat162float(hi.h);
    BFu lo; lo.h = __float2bfloat16(rs);
    return (unsigned)(unsigned short)hi.s | ((unsigned)(unsigned short)lo.s << 16);
}

__global__ void k_init(float* __restrict__ ws) {
    int i = blockIdx.x * 256 + threadIdx.x;
    if (i < 1280) ws[i] = 0.f;
}

// Union-grid kernel (r16 machinery verbatim; r19 single change: z stream split
// 22/10 across the two passes instead of 32/0 — pass 2's idle HBM hides part of
// the 130 MB xh read; z path itself byte-identical to r16).
// blockIdx.x < 64 -> conv pass (MODE); blockIdx.x >= 64 -> z path:
//   z[px] = sum_a xh[px][a]/(band[a]*1e-6)  (pure HBM, overlaps conv).
// Conv: implicit-GEMM, split-bf16 MFMA (r6..r16-verified).
// K-order: slice s in {0,1,2}: k=s*8+e <-> tap (kh=s, jj=e) [jj=kw*3+ci];
//          slice 3: e<3 <-> (kh=e, jj=8); e==3 <-> bias (A=1.0); e>=4 A=1,B=0.
// pan[l*776+j]: row l (0..5) = global row r0-1+l, dword j = packsplit(x float j-3);
// row 6 = packsplit(1.0). A-gather: 8 per-lane ds_read_b32 at off8[e]+48cs+3mrow.
// cw/cb staged to LDS coalesced (r11 fix). MODE 0: per-ch sum/sumsq of y.
// MODE 1: stats inline from ws, BN folded into B-frags, relu+add epilogue, FEAT sums.
template <int MODE>
__global__ __launch_bounds__(256) void k_convz(const float* __restrict__ x,
                                               const float* __restrict__ xh,
                                               const float* __restrict__ cw,
                                               const float* __restrict__ cb,
                                               const float* __restrict__ bnw,
                                               const float* __restrict__ bnb,
                                               float* __restrict__ ws) {
    __shared__ __align__(16) char smem[SM_BYTES];
    const int t = threadIdx.x;
    const int b = blockIdx.y;

    if (blockIdx.x >= 64) {
        // ---------------- z-streaming path (byte-identical to r16) ----------------
        float* s_x = (float*)smem;
        float* s_g = (float*)(smem + SM_G);
        const int zx = (blockIdx.x - 64) + (MODE == 1 ? ZP1 : 0);   // 0..31
        if (t < 31) {
            const float band = 400.f + (300.f * (float)t) / 31.f;
            s_g[t] = 1.f / (band * 1e-6f);
        }
#pragma unroll 1
        for (int c = 0; c < 8; ++c) {
            const size_t pxbase = (size_t)b * 65536 + (size_t)zx * 2048 + c * 256;
            const float4* xg = (const float4*)(xh + pxbase * 31);
            float4* sx4 = (float4*)s_x;
#pragma unroll
            for (int i = 0; i < 8; ++i) {
                int idx = t + (i << 8);
                if (idx < 1984) sx4[idx] = xg[idx];
            }
            __syncthreads();
            float z = 0.f;
            const float* px = s_x + t * 31;
#pragma unroll
            for (int a = 0; a < 31; ++a) z = fmaf(px[a], s_g[a], z);
            ws[OFF_Z + pxbase + t] = z;
            __syncthreads();
        }
        return;
    }

    // ---------------- conv path (r16-verbatim machinery) ----------------
    unsigned* pan32 = (unsigned*)smem;
    float* s_w = (float*)(smem + SM_W);
    float* s_b = (float*)(smem + SM_B);
    float (*red)[4][16][2] = (float (*)[4][16][2])(smem + SM_RED);

    const int lane = t & 63;
    const int wv   = t >> 6;
    const int r0   = blockIdx.x * 4;
    const int mrow = lane & 15;
    const int s    = lane >> 4;
    const bool s3  = (s == 3);
    const float* __restrict__ xb = x + (size_t)b * (HH * WW * 3);

    for (int i = t; i < 1728; i += 256) s_w[i] = cw[i];
    if (t < 64) s_b[t] = cb[t];

    for (int e = t; e < 6 * 774; e += 256) {
        const int l = e / 774, j = e - l * 774;
        const int gr = r0 - 1 + l, gcf = j - 3;
        const bool ok = ((unsigned)gr < 256u) && ((unsigned)gcf < 768u);
        int off = gr * 768 + gcf;
        off = ok ? off : 0;
        float v = xb[off];
        v = ok ? v : 0.f;
        pan32[l * 776 + j] = packsplit(v);
    }
    for (int j = t; j < 776; j += 256) pan32[6 * 776 + j] = 0x3F80u;  // pack(1.0, 0)

    float av[4], bvv[4];
#pragma unroll
    for (int n = 0; n < 4; ++n) {
        const int ch = n * 16 + mrow;
        if (MODE == 1) {
            const float invN = 1.f / 1048576.f;
            const float mu = ws[OFF_CHSUM + ch] * invN;
            const float vr = ws[OFF_CHSQ + ch] * invN - mu * mu;
            const float rs = rsqrtf(vr + 1e-5f);
            av[n]  = rs * bnw[ch];
            bvv[n] = bnb[ch] - mu * av[n];
        } else { av[n] = 1.f; bvv[n] = 0.f; }
    }

    int off8[8];
#pragma unroll
    for (int e = 0; e < 8; ++e) {
        if (!s3)        off8[e] = (wv + s) * 776 + e;
        else if (e < 3) off8[e] = (wv + e) * 776 + 8;
        else            off8[e] = 6 * 776 + e;
    }
    const int mrow3 = mrow * 3;

    __syncthreads();

    bf16x8 bh[4], bl[4];
#pragma unroll
    for (int n = 0; n < 4; ++n) {
        const int ch = n * 16 + mrow;
#pragma unroll
        for (int e = 0; e < 8; ++e) {
            float w = 0.f;
            if (!s3) {
                w = s_w[ch * 27 + (e % 3) * 9 + s * 3 + (e / 3)];
            } else if (e < 3) {
                w = s_w[ch * 27 + 18 + e * 3 + 2];
            } else if (e == 3) {
                w = s_b[ch];
            }
            if (MODE == 1) {
                w *= av[n];
                if (s3 && e == 3) w += bvv[n];
            }
            BFu hi; hi.h = __float2bfloat16(w);
            const float rs2 = w - __bfloat162float(hi.h);
            BFu lo; lo.h = __float2bfloat16(rs2);
            bh[n][e] = hi.s;
            bl[n][e] = lo.s;
        }
    }

    float a0[4] = {0.f, 0.f, 0.f, 0.f};
    float a1[4] = {0.f, 0.f, 0.f, 0.f};

#define GATHER(W, CS)                                                   \
    {                                                                   \
        const int c3 = (CS) * 48 + mrow3;                               \
        W[0] = pan32[off8[0] + c3]; W[1] = pan32[off8[1] + c3];         \
        W[2] = pan32[off8[2] + c3]; W[3] = pan32[off8[3] + c3];         \
        W[4] = pan32[off8[4] + c3]; W[5] = pan32[off8[5] + c3];         \
        W[6] = pan32[off8[6] + c3]; W[7] = pan32[off8[7] + c3];         \
    }
#define COMPUTE(W)                                                      \
    {                                                                   \
        ABu ua, ul;                                                     \
        ua.u[0] = __builtin_amdgcn_perm(W[1], W[0], 0x05040100u);       \
        ua.u[1] = __builtin_amdgcn_perm(W[3], W[2], 0x05040100u);       \
        ua.u[2] = __builtin_amdgcn_perm(W[5], W[4], 0x05040100u);       \
        ua.u[3] = __builtin_amdgcn_perm(W[7], W[6], 0x05040100u);       \
        ul.u[0] = __builtin_amdgcn_perm(W[1], W[0], 0x07060302u);       \
        ul.u[1] = __builtin_amdgcn_perm(W[3], W[2], 0x07060302u);       \
        ul.u[2] = __builtin_amdgcn_perm(W[5], W[4], 0x07060302u);       \
        ul.u[3] = __builtin_amdgcn_perm(W[7], W[6], 0x07060302u);       \
        const bf16x8 ah = ua.v, al = ul.v;                              \
        __builtin_amdgcn_s_setprio(1);                                  \
        _Pragma("unroll")                                               \
        for (int n = 0; n < 4; ++n) {                                   \
            f32x4 acc = {0.f, 0.f, 0.f, 0.f};                           \
            acc = __builtin_amdgcn_mfma_f32_16x16x32_bf16(ah, bl[n], acc, 0, 0, 0); \
            acc = __builtin_amdgcn_mfma_f32_16x16x32_bf16(al, bh[n], acc, 0, 0, 0); \
            acc = __builtin_amdgcn_mfma_f32_16x16x32_bf16(ah, bh[n], acc, 0, 0, 0); \
            _Pragma("unroll")                                           \
            for (int i = 0; i < 4; ++i) {                               \
                const float y = acc[i];                                 \
                if (MODE == 0) { a0[n] += y; a1[n] = fmaf(y, y, a1[n]); } \
                else { a0[n] += fmaxf(y, 0.f); }                        \
            }                                                           \
        }                                                               \
        __builtin_amdgcn_s_setprio(0);                                  \
    }

    {
        unsigned Wa[8], Wb[8];
        GATHER(Wa, 0)
        GATHER(Wb, 1)  COMPUTE(Wa)
        GATHER(Wa, 2)  COMPUTE(Wb)
        GATHER(Wb, 3)  COMPUTE(Wa)
        GATHER(Wa, 4)  COMPUTE(Wb)
        GATHER(Wb, 5)  COMPUTE(Wa)
        GATHER(Wa, 6)  COMPUTE(Wb)
        GATHER(Wb, 7)  COMPUTE(Wa)
        GATHER(Wa, 8)  COMPUTE(Wb)
        GATHER(Wb, 9)  COMPUTE(Wa)
        GATHER(Wa, 10) COMPUTE(Wb)
        GATHER(Wb, 11) COMPUTE(Wa)
        GATHER(Wa, 12) COMPUTE(Wb)
        GATHER(Wb, 13) COMPUTE(Wa)
        GATHER(Wa, 14) COMPUTE(Wb)
        GATHER(Wb, 15) COMPUTE(Wa)
        COMPUTE(Wb)
    }
#undef GATHER
#undef COMPUTE

#pragma unroll
    for (int n = 0; n < 4; ++n) {
        a0[n] += __shfl_xor(a0[n], 16);
        a0[n] += __shfl_xor(a0[n], 32);
        if (MODE == 0) {
            a1[n] += __shfl_xor(a1[n], 16);
            a1[n] += __shfl_xor(a1[n], 32);
        }
    }
    if (lane < 16) {
#pragma unroll
        for (int n = 0; n < 4; ++n) {
            red[wv][n][lane][0] = a0[n];
            red[wv][n][lane][1] = (MODE == 0) ? a1[n] : 0.f;
        }
    }
    __syncthreads();
    if (t < 64) {
        const int n = t >> 4, m = t & 15;
        const float S = red[0][n][m][0] + red[1][n][m][0] + red[2][n][m][0] + red[3][n][m][0];
        if (MODE == 0) {
            const float Q = red[0][n][m][1] + red[1][n][m][1] + red[2][n][m][1] + red[3][n][m][1];
            atomicAdd(&ws[OFF_CHSUM + t], S);
            atomicAdd(&ws[OFF_CHSQ + t], Q);
        } else {
            atomicAdd(&ws[OFF_FEAT + b * 64 + t], S);
        }
    }
}

// out[px][c] = p[b][c] * z[px]; z precomputed in ws by the union kernels.
__global__ __launch_bounds__(256) void k_final2(const float* __restrict__ fcw,
                                                const float* __restrict__ fcb,
                                                const float* __restrict__ ws,
                                                float* __restrict__ out) {
    __shared__ float s_raw[5];
    __shared__ float sp[3];
    __shared__ float s_o[768];
    const int t = threadIdx.x;
    const int blk = blockIdx.x;
    const int b = blk >> 8;
    const size_t pix0 = (size_t)blk << 8;

    if (t < 5) {
        const float inv = 1.f / 65536.f;
        float a = fcb[t];
        for (int c = 0; c < 64; ++c)
            a = fmaf(fcw[t * 64 + c], ws[OFF_FEAT + b * 64 + c] * inv, a);
        s_raw[t] = a;
    }
    __syncthreads();
    if (t == 0) {
        float raw[5];
#pragma unroll
        for (int j = 0; j < 5; ++j) raw[j] = s_raw[j];
#define CS(i, j)                              \
        {                                     \
            float lo = fminf(raw[i], raw[j]); \
            float hi = fmaxf(raw[i], raw[j]); \
            raw[i] = lo;                      \
            raw[j] = hi;                      \
        }
        CS(0, 1) CS(3, 4) CS(2, 4) CS(2, 3) CS(0, 3) CS(0, 2) CS(1, 4) CS(1, 3) CS(1, 2)
#undef CS
        const float mn = raw[0], mx = raw[4];
        const float sc = 10.f / (mx - mn + 1e-8f);
#pragma unroll
        for (int c2 = 0; c2 < 3; ++c2) {
            const float v = (raw[1 + c2] - mn) * sc;
            const float sh = sinf(0.031415926535897934f / v);
            sp[c2] = sh * sh;
        }
    }
    __syncthreads();
    const float z = ws[OFF_Z + pix0 + t];
    s_o[t * 3 + 0] = sp[0] * z;
    s_o[t * 3 + 1] = sp[1] * z;
    s_o[t * 3 + 2] = sp[2] * z;
    __syncthreads();
    float* ob = out + pix0 * 3;
#pragma unroll
    for (int i = 0; i < 3; ++i) ob[t + (i << 8)] = s_o[t + (i << 8)];
}

extern "C" void kernel_launch(void* const* d_in, const int* in_sizes, int n_in,
                              void* d_out, int out_size, void* d_ws, size_t ws_size,
                              hipStream_t stream) {
    const float* x    = (const float*)d_in[0];
    const float* xhsi = (const float*)d_in[1];
    const float* cw   = (const float*)d_in[2];
    const float* cb   = (const float*)d_in[3];
    const float* bnw  = (const float*)d_in[4];
    const float* bnb  = (const float*)d_in[5];
    const float* fcw  = (const float*)d_in[6];
    const float* fcb  = (const float*)d_in[7];
    float* out = (float*)d_out;
    float* ws  = (float*)d_ws;

    hipLaunchKernelGGL(k_init, dim3(5), dim3(256), 0, stream, ws);
    // pass 1: x<64 conv-stats, x in [64, 64+ZP1) = z-units 0..21
    hipLaunchKernelGGL((k_convz<0>), dim3(64 + ZP1, 16), dim3(256), 0, stream,
                       x, xhsi, cw, cb, bnw, bnb, ws);
    // pass 2: x<64 conv-BN-pool, x in [64, 64+ZP2) = z-units 22..31
    hipLaunchKernelGGL((k_convz<1>), dim3(64 + ZP2, 16), dim3(256), 0, stream,
                       x, xhsi, cw, cb, bnw, bnb, ws);
    hipLaunchKernelGGL(k_final2, dim3(4096), dim3(256), 0, stream, fcw, fcb, ws, out);
}

// Round 20
// 81.026 us; speedup vs baseline: 1.1497x; 1.1497x over previous
//
#include <hip/hip_runtime.h>
#include <hip/hip_bf16.h>
#include <math.h>

#define BB 16
#define HH 256
#define WW 256

// ws layout in floats
#define OFF_CHSUM 0      // [64]
#define OFF_CHSQ  64     // [64]
#define OFF_FEAT  256    // [16*64] pooled relu sums (pre-division)
#define OFF_Z     2048   // [16*256*256] z = sum_a g[a]*xh[px][a]

// shared-memory pool byte offsets (conv path)
#define SM_PAN   0                   // unsigned[7*776]  = 21728 B
#define SM_W     21728               // float[1728]      =  6912 B
#define SM_B     28640               // float[64]        =   256 B
#define SM_RED   28896               // float[4][4][16][2] = 2048 B -> 30944
// z path: float[256*31] = 31744 B at 0; g table at 31744 (+128)
#define SM_G     31744
#define SM_BYTES 32000

typedef __attribute__((ext_vector_type(8))) short bf16x8;
typedef __attribute__((ext_vector_type(4))) float f32x4;

union BFu { __hip_bfloat16 h; short s; };
union ABu { bf16x8 v; unsigned u[4]; };

__device__ __forceinline__ unsigned packsplit(float v) {
    BFu hi; hi.h = __float2bfloat16(v);
    float rs = v - __bfloat162float(hi.h);
    BFu lo; lo.h = __float2bfloat16(rs);
    return (unsigned)(unsigned short)hi.s | ((unsigned)(unsigned short)lo.s << 16);
}

__global__ void k_init(float* __restrict__ ws) {
    int i = blockIdx.x * 256 + threadIdx.x;
    if (i < 1280) ws[i] = 0.f;
}

// Union-grid kernel — r16 verbatim (best measured config: all 32 z-units under
// pass 1; r19's split regressed). blockIdx.x < 64 -> conv pass (MODE);
// blockIdx.x >= 64 (MODE 0 launch only) -> z path:
//   z[px] = sum_a xh[px][a]/(band[a]*1e-6)  (pure HBM, overlaps conv pass 1).
// Conv: implicit-GEMM, split-bf16 MFMA (r6..r16-verified).
// K-order: slice s in {0,1,2}: k=s*8+e <-> tap (kh=s, jj=e) [jj=kw*3+ci];
//          slice 3: e<3 <-> (kh=e, jj=8); e==3 <-> bias (A=1.0); e>=4 A=1,B=0.
// pan[l*776+j]: row l (0..5) = global row r0-1+l, dword j = packsplit(x float j-3);
// row 6 = packsplit(1.0). A-gather: 8 per-lane ds_read_b32 at off8[e]+48cs+3mrow.
// cw/cb staged to LDS coalesced (r11 fix). MODE 0: per-ch sum/sumsq of y.
// MODE 1: stats inline from ws, BN folded into B-frags, relu+add epilogue, FEAT sums.
template <int MODE>
__global__ __launch_bounds__(256) void k_convz(const float* __restrict__ x,
                                               const float* __restrict__ xh,
                                               const float* __restrict__ cw,
                                               const float* __restrict__ cb,
                                               const float* __restrict__ bnw,
                                               const float* __restrict__ bnb,
                                               float* __restrict__ ws) {
    __shared__ __align__(16) char smem[SM_BYTES];
    const int t = threadIdx.x;
    const int b = blockIdx.y;

    if (blockIdx.x >= 64) {
        // ---------------- z-streaming path ----------------
        float* s_x = (float*)smem;
        float* s_g = (float*)(smem + SM_G);
        const int zx = blockIdx.x - 64;            // 0..31
        if (t < 31) {
            const float band = 400.f + (300.f * (float)t) / 31.f;
            s_g[t] = 1.f / (band * 1e-6f);
        }
#pragma unroll 1
        for (int c = 0; c < 8; ++c) {
            const size_t pxbase = (size_t)b * 65536 + zx * 2048 + c * 256;
            const float4* xg = (const float4*)(xh + pxbase * 31);
            float4* sx4 = (float4*)s_x;
#pragma unroll
            for (int i = 0; i < 8; ++i) {
                int idx = t + (i << 8);
                if (idx < 1984) sx4[idx] = xg[idx];
            }
            __syncthreads();
            float z = 0.f;
            const float* px = s_x + t * 31;
#pragma unroll
            for (int a = 0; a < 31; ++a) z = fmaf(px[a], s_g[a], z);
            ws[OFF_Z + pxbase + t] = z;
            __syncthreads();
        }
        return;
    }

    // ---------------- conv path (r11-verbatim machinery) ----------------
    unsigned* pan32 = (unsigned*)smem;
    float* s_w = (float*)(smem + SM_W);
    float* s_b = (float*)(smem + SM_B);
    float (*red)[4][16][2] = (float (*)[4][16][2])(smem + SM_RED);

    const int lane = t & 63;
    const int wv   = t >> 6;
    const int r0   = blockIdx.x * 4;
    const int mrow = lane & 15;
    const int s    = lane >> 4;
    const bool s3  = (s == 3);
    const float* __restrict__ xb = x + (size_t)b * (HH * WW * 3);

    for (int i = t; i < 1728; i += 256) s_w[i] = cw[i];
    if (t < 64) s_b[t] = cb[t];

    for (int e = t; e < 6 * 774; e += 256) {
        const int l = e / 774, j = e - l * 774;
        const int gr = r0 - 1 + l, gcf = j - 3;
        const bool ok = ((unsigned)gr < 256u) && ((unsigned)gcf < 768u);
        int off = gr * 768 + gcf;
        off = ok ? off : 0;
        float v = xb[off];
        v = ok ? v : 0.f;
        pan32[l * 776 + j] = packsplit(v);
    }
    for (int j = t; j < 776; j += 256) pan32[6 * 776 + j] = 0x3F80u;  // pack(1.0, 0)

    float av[4], bvv[4];
#pragma unroll
    for (int n = 0; n < 4; ++n) {
        const int ch = n * 16 + mrow;
        if (MODE == 1) {
            const float invN = 1.f / 1048576.f;
            const float mu = ws[OFF_CHSUM + ch] * invN;
            const float vr = ws[OFF_CHSQ + ch] * invN - mu * mu;
            const float rs = rsqrtf(vr + 1e-5f);
            av[n]  = rs * bnw[ch];
            bvv[n] = bnb[ch] - mu * av[n];
        } else { av[n] = 1.f; bvv[n] = 0.f; }
    }

    int off8[8];
#pragma unroll
    for (int e = 0; e < 8; ++e) {
        if (!s3)        off8[e] = (wv + s) * 776 + e;
        else if (e < 3) off8[e] = (wv + e) * 776 + 8;
        else            off8[e] = 6 * 776 + e;
    }
    const int mrow3 = mrow * 3;

    __syncthreads();

    bf16x8 bh[4], bl[4];
#pragma unroll
    for (int n = 0; n < 4; ++n) {
        const int ch = n * 16 + mrow;
#pragma unroll
        for (int e = 0; e < 8; ++e) {
            float w = 0.f;
            if (!s3) {
                w = s_w[ch * 27 + (e % 3) * 9 + s * 3 + (e / 3)];
            } else if (e < 3) {
                w = s_w[ch * 27 + 18 + e * 3 + 2];
            } else if (e == 3) {
                w = s_b[ch];
            }
            if (MODE == 1) {
                w *= av[n];
                if (s3 && e == 3) w += bvv[n];
            }
            BFu hi; hi.h = __float2bfloat16(w);
            const float rs2 = w - __bfloat162float(hi.h);
            BFu lo; lo.h = __float2bfloat16(rs2);
            bh[n][e] = hi.s;
            bl[n][e] = lo.s;
        }
    }

    float a0[4] = {0.f, 0.f, 0.f, 0.f};
    float a1[4] = {0.f, 0.f, 0.f, 0.f};

#define GATHER(W, CS)                                                   \
    {                                                                   \
        const int c3 = (CS) * 48 + mrow3;                               \
        W[0] = pan32[off8[0] + c3]; W[1] = pan32[off8[1] + c3];         \
        W[2] = pan32[off8[2] + c3]; W[3] = pan32[off8[3] + c3];         \
        W[4] = pan32[off8[4] + c3]; W[5] = pan32[off8[5] + c3];         \
        W[6] = pan32[off8[6] + c3]; W[7] = pan32[off8[7] + c3];         \
    }
#define COMPUTE(W)                                                      \
    {                                                                   \
        ABu ua, ul;                                                     \
        ua.u[0] = __builtin_amdgcn_perm(W[1], W[0], 0x05040100u);       \
        ua.u[1] = __builtin_amdgcn_perm(W[3], W[2], 0x05040100u);       \
        ua.u[2] = __builtin_amdgcn_perm(W[5], W[4], 0x05040100u);       \
        ua.u[3] = __builtin_amdgcn_perm(W[7], W[6], 0x05040100u);       \
        ul.u[0] = __builtin_amdgcn_perm(W[1], W[0], 0x07060302u);       \
        ul.u[1] = __builtin_amdgcn_perm(W[3], W[2], 0x07060302u);       \
        ul.u[2] = __builtin_amdgcn_perm(W[5], W[4], 0x07060302u);       \
        ul.u[3] = __builtin_amdgcn_perm(W[7], W[6], 0x07060302u);       \
        const bf16x8 ah = ua.v, al = ul.v;                              \
        __builtin_amdgcn_s_setprio(1);                                  \
        _Pragma("unroll")                                               \
        for (int n = 0; n < 4; ++n) {                                   \
            f32x4 acc = {0.f, 0.f, 0.f, 0.f};                           \
            acc = __builtin_amdgcn_mfma_f32_16x16x32_bf16(ah, bl[n], acc, 0, 0, 0); \
            acc = __builtin_amdgcn_mfma_f32_16x16x32_bf16(al, bh[n], acc, 0, 0, 0); \
            acc = __builtin_amdgcn_mfma_f32_16x16x32_bf16(ah, bh[n], acc, 0, 0, 0); \
            _Pragma("unroll")                                           \
            for (int i = 0; i < 4; ++i) {                               \
                const float y = acc[i];                                 \
                if (MODE == 0) { a0[n] += y; a1[n] = fmaf(y, y, a1[n]); } \
                else { a0[n] += fmaxf(y, 0.f); }                        \
            }                                                           \
        }                                                               \
        __builtin_amdgcn_s_setprio(0);                                  \
    }

    {
        unsigned Wa[8], Wb[8];
        GATHER(Wa, 0)
        GATHER(Wb, 1)  COMPUTE(Wa)
        GATHER(Wa, 2)  COMPUTE(Wb)
        GATHER(Wb, 3)  COMPUTE(Wa)
        GATHER(Wa, 4)  COMPUTE(Wb)
        GATHER(Wb, 5)  COMPUTE(Wa)
        GATHER(Wa, 6)  COMPUTE(Wb)
        GATHER(Wb, 7)  COMPUTE(Wa)
        GATHER(Wa, 8)  COMPUTE(Wb)
        GATHER(Wb, 9)  COMPUTE(Wa)
        GATHER(Wa, 10) COMPUTE(Wb)
        GATHER(Wb, 11) COMPUTE(Wa)
        GATHER(Wa, 12) COMPUTE(Wb)
        GATHER(Wb, 13) COMPUTE(Wa)
        GATHER(Wa, 14) COMPUTE(Wb)
        GATHER(Wb, 15) COMPUTE(Wa)
        COMPUTE(Wb)
    }
#undef GATHER
#undef COMPUTE

#pragma unroll
    for (int n = 0; n < 4; ++n) {
        a0[n] += __shfl_xor(a0[n], 16);
        a0[n] += __shfl_xor(a0[n], 32);
        if (MODE == 0) {
            a1[n] += __shfl_xor(a1[n], 16);
            a1[n] += __shfl_xor(a1[n], 32);
        }
    }
    if (lane < 16) {
#pragma unroll
        for (int n = 0; n < 4; ++n) {
            red[wv][n][lane][0] = a0[n];
            red[wv][n][lane][1] = (MODE == 0) ? a1[n] : 0.f;
        }
    }
    __syncthreads();
    if (t < 64) {
        const int n = t >> 4, m = t & 15;
        const float S = red[0][n][m][0] + red[1][n][m][0] + red[2][n][m][0] + red[3][n][m][0];
        if (MODE == 0) {
            const float Q = red[0][n][m][1] + red[1][n][m][1] + red[2][n][m][1] + red[3][n][m][1];
            atomicAdd(&ws[OFF_CHSUM + t], S);
            atomicAdd(&ws[OFF_CHSQ + t], Q);
        } else {
            atomicAdd(&ws[OFF_FEAT + b * 64 + t], S);
        }
    }
}

// out[px][c] = p[b][c] * z[px]; z precomputed in ws by the union kernel.
// r20: 1024 px/block (grid 1024), z staged via float4, out written as float4.
__global__ __launch_bounds__(256) void k_final3(const float* __restrict__ fcw,
                                                const float* __restrict__ fcb,
                                                const float* __restrict__ ws,
                                                float* __restrict__ out) {
    __shared__ float s_z[1024];
    __shared__ float s_raw[5];
    __shared__ float sp[3];
    const int t = threadIdx.x;
    const int blk = blockIdx.x;          // 0..1023
    const int b = blk >> 6;              // 64 blocks per image
    const size_t pix0 = (size_t)blk << 10;

    if (t < 5) {
        const float inv = 1.f / 65536.f;
        float a = fcb[t];
        for (int c = 0; c < 64; ++c)
            a = fmaf(fcw[t * 64 + c], ws[OFF_FEAT + b * 64 + c] * inv, a);
        s_raw[t] = a;
    }
    // stage 1024 z values (coalesced float4)
    ((float4*)s_z)[t] = ((const float4*)(ws + OFF_Z + pix0))[t];
    __syncthreads();
    if (t == 0) {
        float raw[5];
#pragma unroll
        for (int j = 0; j < 5; ++j) raw[j] = s_raw[j];
#define CS(i, j)                              \
        {                                     \
            float lo = fminf(raw[i], raw[j]); \
            float hi = fmaxf(raw[i], raw[j]); \
            raw[i] = lo;                      \
            raw[j] = hi;                      \
        }
        CS(0, 1) CS(3, 4) CS(2, 4) CS(2, 3) CS(0, 3) CS(0, 2) CS(1, 4) CS(1, 3) CS(1, 2)
#undef CS
        const float mn = raw[0], mx = raw[4];
        const float sc = 10.f / (mx - mn + 1e-8f);
#pragma unroll
        for (int c2 = 0; c2 < 3; ++c2) {
            const float v = (raw[1 + c2] - mn) * sc;
            const float sh = sinf(0.031415926535897934f / v);
            sp[c2] = sh * sh;
        }
    }
    __syncthreads();
    // write 3072 floats = 768 float4 (3 per thread), fully coalesced
    float4* ob = (float4*)(out + pix0 * 3);
#pragma unroll
    for (int k = 0; k < 3; ++k) {
        const int j = t + (k << 8);      // float4 index 0..767
        const int f = 4 * j;             // flat float index within block
        float4 v;
        v.x = sp[(f + 0) % 3] * s_z[(f + 0) / 3];
        v.y = sp[(f + 1) % 3] * s_z[(f + 1) / 3];
        v.z = sp[(f + 2) % 3] * s_z[(f + 2) / 3];
        v.w = sp[(f + 3) % 3] * s_z[(f + 3) / 3];
        ob[j] = v;
    }
}

extern "C" void kernel_launch(void* const* d_in, const int* in_sizes, int n_in,
                              void* d_out, int out_size, void* d_ws, size_t ws_size,
                              hipStream_t stream) {
    const float* x    = (const float*)d_in[0];
    const float* xhsi = (const float*)d_in[1];
    const float* cw   = (const float*)d_in[2];
    const float* cb   = (const float*)d_in[3];
    const float* bnw  = (const float*)d_in[4];
    const float* bnb  = (const float*)d_in[5];
    const float* fcw  = (const float*)d_in[6];
    const float* fcb  = (const float*)d_in[7];
    float* out = (float*)d_out;
    float* ws  = (float*)d_ws;

    hipLaunchKernelGGL(k_init, dim3(5), dim3(256), 0, stream, ws);
    // union grid: x<64 = conv pass 1 (stats), x>=64 = z-streaming (overlapped)
    hipLaunchKernelGGL((k_convz<0>), dim3(96, 16), dim3(256), 0, stream,
                       x, xhsi, cw, cb, bnw, bnb, ws);
    // pass 2: conv blocks only
    hipLaunchKernelGGL((k_convz<1>), dim3(64, 16), dim3(256), 0, stream,
                       x, xhsi, cw, cb, bnw, bnb, ws);
    hipLaunchKernelGGL(k_final3, dim3(1024), dim3(256), 0, stream, fcw, fcb, ws, out);
}